// Round 1
// baseline (216.482 us; speedup 1.0000x reference)
//
#include <hip/hip_runtime.h>

// FirstSpikeDetector: out[b][t] = 1.0 iff t is the first index where
// spike_train[b][t] != 0, else 0.0.
//
// Fused single-dispatch version:
//   - One wave64 per row. Phase 1: lanes scan 64 floats at a time (256 B
//     coalesced), __ballot + __ffsll finds the first spike lane; at ~10%
//     firing rate P(resolve in iter 0) = 1 - 0.9^64 ~= 0.9988, so read
//     traffic ~= 16384 x 256 B ~= 4 MB.
//   - Phase 2: the wave rewrites its ENTIRE row (2048 floats = 8 KB) with
//     float4 stores: zeros everywhere, 1.0 at the first-spike index. This
//     replaces the separate hipMemsetAsync, whose size was provably 4x the
//     output (rocprof WRITE_SIZE = 512 MiB vs 128 MiB output => out_size is
//     in BYTES, and out_size*sizeof(float) quadrupled the fill). Writing
//     exactly batch*T*4 B from the kernel sidesteps the convention entirely.
//
// Floor: 128 MiB streaming write ~= 20 us at the measured 6.6 TB/s fill rate.

__global__ __launch_bounds__(256, 4) void first_spike_fused(
    const float* __restrict__ in, float* __restrict__ out, int batch, int T) {
  const int lane = threadIdx.x & 63;
  const int wave = threadIdx.x >> 6;
  const int row  = blockIdx.x * 4 + wave;
  if (row >= batch) return;  // wave-uniform

  const float* __restrict__ rowp = in + (size_t)row * T;

  // Phase 1: find first nonzero index in the row (-1 if none).
  int idx = -1;
  const int riters = T >> 6;  // 64 elems per iteration
  for (int it = 0; it < riters; ++it) {
    float v = rowp[(it << 6) + lane];
    unsigned long long mask = __ballot(v != 0.0f);
    if (mask) {  // wave-uniform
      idx = (it << 6) + (__ffsll(mask) - 1);
      break;
    }
  }

  // Phase 2: write the whole row: zeros + single 1.0 at idx.
  float* __restrict__ outp = out + (size_t)row * T;
  const int witers = T >> 8;  // 64 lanes x 4 floats = 256 floats per iter
  for (int it = 0; it < witers; ++it) {
    const int base = (it << 8) + (lane << 2);
    float4 v = make_float4(0.0f, 0.0f, 0.0f, 0.0f);
    if ((unsigned)(idx - base) < 4u) {  // true only for the owning lane
      reinterpret_cast<float*>(&v)[idx - base] = 1.0f;
    }
    *reinterpret_cast<float4*>(outp + base) = v;  // 16 B/lane, contiguous row
  }
}

extern "C" void kernel_launch(void* const* d_in, const int* in_sizes, int n_in,
                              void* d_out, int out_size, void* d_ws, size_t ws_size,
                              hipStream_t stream) {
  const float* in = (const float*)d_in[0];
  float* out = (float*)d_out;
  const int T = 2048;                 // time axis per reference setup_inputs
  const int batch = in_sizes[0] / T;  // 16384 (in_sizes is element count)

  const int waves_per_block = 4;  // 256 threads = 4 wave64, one row each
  dim3 grid((batch + waves_per_block - 1) / waves_per_block);
  first_spike_fused<<<grid, 256, 0, stream>>>(in, out, batch, T);
}

// Round 2
// 199.257 us; speedup vs baseline: 1.0864x; 1.0864x over previous
//
#include <hip/hip_runtime.h>

// FirstSpikeDetector: out[b][t] = 1.0 iff t is the first index where
// spike_train[b][t] != 0, else 0.0. (NOT/AND/OR gate cascade over a scan
// collapses to "keep only the first spike per row".)
//
// Decomposition (calibrated variant):
//   1. hipMemsetAsync(d_out, 0, batch*T*4)  -- EXACTLY 128 MiB (the round-0
//      version passed out_size*sizeof(float); rocprof showed out_size is
//      already in BYTES, so that fill was 512 MiB = 4x oversized, 81 us
//      instead of ~20 us). Byte count is now derived from batch*T directly,
//      independent of the out_size convention.
//   2. first_spike_scatter -- one wave64 per row; lanes read 64 floats
//      (256 B coalesced), __ballot + __ffsll finds the first spike lane,
//      lane 0 stores a single 1.0f. At ~10% firing rate P(resolve in iter 0)
//      = 1 - 0.9^64 ~= 0.9988, so read traffic ~= 16384 x 256 B ~= 4 MB,
//      write traffic ~= 16384 x 4 B. ~5 us.
//
// Evidence so far (rounds 0-1): the timed window also contains the harness's
// own 512 MiB re-poison fills (~80 us each @ 83% HBM peak) -- they persist
// in rocprof even when we enqueue no fill. Our enqueued floor is ~25 us:
// one irreducible 128 MiB zero-write at fill-engine rate + the tiny scatter.

__global__ __launch_bounds__(256, 4) void first_spike_scatter(
    const float* __restrict__ in, float* __restrict__ out, int batch, int T) {
  const int lane = threadIdx.x & 63;
  const int wave = threadIdx.x >> 6;
  const int row  = blockIdx.x * 4 + wave;
  if (row >= batch) return;  // wave-uniform

  const float* __restrict__ rowp = in + (size_t)row * T;
  const int iters = T >> 6;  // 64 elems per iteration

  for (int it = 0; it < iters; ++it) {
    float v = rowp[(it << 6) + lane];
    unsigned long long mask = __ballot(v != 0.0f);
    if (mask) {  // wave-uniform
      if (lane == 0) {
        int idx = (it << 6) + (__ffsll(mask) - 1);  // first set lane = first spike
        out[(size_t)row * T + idx] = 1.0f;
      }
      return;
    }
  }
  // no spike in this row: all zeros, nothing to store
}

extern "C" void kernel_launch(void* const* d_in, const int* in_sizes, int n_in,
                              void* d_out, int out_size, void* d_ws, size_t ws_size,
                              hipStream_t stream) {
  const float* in = (const float*)d_in[0];
  float* out = (float*)d_out;
  const int T = 2048;                 // time axis per reference setup_inputs
  const int batch = in_sizes[0] / T;  // in_sizes[0] is ELEMENTS (proven: round-1
                                      // passed with this batch writing batch*T floats)

  // Zero exactly the logical output: batch*T floats = 128 MiB. Capture-safe
  // (becomes a graph memset node).
  hipMemsetAsync(d_out, 0, (size_t)batch * T * sizeof(float), stream);

  const int waves_per_block = 4;  // 256 threads = 4 wave64, one row each
  dim3 grid((batch + waves_per_block - 1) / waves_per_block);
  first_spike_scatter<<<grid, 256, 0, stream>>>(in, out, batch, T);
}